// Round 1
// baseline (168.913 us; speedup 1.0000x reference)
//
#include <hip/hip_runtime.h>
#include <math.h>

#define TW 32
#define TH 32
#define RW (TW + 10)   // 42
#define RH (TH + 10)   // 42
#define IMG_W 512
#define OUT_W 502      // 512 - 11 + 1
#define CH_STRIDE (3 * IMG_W * IMG_W)

__global__ __launch_bounds__(256) void ssim_tile_kernel(
    const float* __restrict__ sr_img,
    const float* __restrict__ hr_img,
    float* __restrict__ accum)
{
    __shared__ float s_hr[RH][RW];
    __shared__ float s_sr[RH][RW];
    __shared__ float h_m1[RH][TW];
    __shared__ float h_m2[RH][TW];
    __shared__ float h_x2[RH][TW];
    __shared__ float h_y2[RH][TW];
    __shared__ float h_xy[RH][TW];
    __shared__ float red[256];

    const int tid = threadIdx.x;
    const int x0 = blockIdx.x * TW;
    const int y0 = blockIdx.y * TH;
    const int b  = blockIdx.z;

    // 1D Gaussian window (normalized). Separable: g2d[i][j] = w[i]*w[j].
    float w[11];
    {
        float s = 0.f;
#pragma unroll
        for (int i = 0; i < 11; ++i) {
            float d = (float)(i - 5);
            w[i] = expf(-d * d / 4.5f);
            s += w[i];
        }
        float inv = 1.f / s;
#pragma unroll
        for (int i = 0; i < 11; ++i) w[i] *= inv;
    }

    const float* __restrict__ hrp = hr_img + (size_t)b * CH_STRIDE;  // channel 0
    const float* __restrict__ srp = sr_img + (size_t)b * CH_STRIDE;

    // Stage raw tile (clamped; out-of-range values only feed invalid outputs)
    for (int idx = tid; idx < RH * RW; idx += 256) {
        int r = idx / RW, c = idx - r * RW;
        int gy = y0 + r; if (gy > IMG_W - 1) gy = IMG_W - 1;
        int gx = x0 + c; if (gx > IMG_W - 1) gx = IMG_W - 1;
        s_hr[r][c] = hrp[gy * IMG_W + gx];
        s_sr[r][c] = srp[gy * IMG_W + gx];
    }
    __syncthreads();

    // Horizontal 11-tap pass over 5 fields
    for (int idx = tid; idx < RH * TW; idx += 256) {
        int r = idx / TW, c = idx - r * TW;
        float m1 = 0.f, m2 = 0.f, x2 = 0.f, y2 = 0.f, xy = 0.f;
#pragma unroll
        for (int k = 0; k < 11; ++k) {
            float a  = s_hr[r][c + k];
            float bb = s_sr[r][c + k];
            float wk = w[k];
            m1 += wk * a;
            m2 += wk * bb;
            x2 += wk * a * a;
            y2 += wk * bb * bb;
            xy += wk * a * bb;
        }
        h_m1[r][c] = m1; h_m2[r][c] = m2;
        h_x2[r][c] = x2; h_y2[r][c] = y2; h_xy[r][c] = xy;
    }
    __syncthreads();

    // Vertical 11-tap pass + SSIM + local accumulation
    const float C1 = 1e-4f, C2 = 9e-4f;
    float local = 0.f;
    for (int idx = tid; idx < TH * TW; idx += 256) {
        int r = idx / TW, c = idx - r * TW;
        int oy = y0 + r, ox = x0 + c;
        if (oy < OUT_W && ox < OUT_W) {
            float m1 = 0.f, m2 = 0.f, x2 = 0.f, y2 = 0.f, xy = 0.f;
#pragma unroll
            for (int k = 0; k < 11; ++k) {
                float wk = w[k];
                m1 += wk * h_m1[r + k][c];
                m2 += wk * h_m2[r + k][c];
                x2 += wk * h_x2[r + k][c];
                y2 += wk * h_y2[r + k][c];
                xy += wk * h_xy[r + k][c];
            }
            float mu1s = m1 * m1, mu2s = m2 * m2, m12 = m1 * m2;
            float s1 = x2 - mu1s, s2 = y2 - mu2s, s12 = xy - m12;
            float num = (2.f * m12 + C1) * (2.f * s12 + C2);
            float den = (mu1s + mu2s + C1) * (s1 + s2 + C2);
            local += num / den;
        }
    }

    // Block reduction
    red[tid] = local;
    __syncthreads();
    for (int s = 128; s > 0; s >>= 1) {
        if (tid < s) red[tid] += red[tid + s];
        __syncthreads();
    }
    if (tid == 0) atomicAdd(accum, red[0]);
}

__global__ void ssim_finalize(const float* __restrict__ accum, float* __restrict__ out)
{
    out[0] = accum[0] * (1.0f / (16.0f * 502.0f * 502.0f));
}

extern "C" void kernel_launch(void* const* d_in, const int* in_sizes, int n_in,
                              void* d_out, int out_size, void* d_ws, size_t ws_size,
                              hipStream_t stream)
{
    const float* sr = (const float*)d_in[0];  // sr_image
    const float* hr = (const float*)d_in[1];  // hr_image
    float* out = (float*)d_out;
    float* accum = (float*)d_ws;

    hipMemsetAsync(accum, 0, sizeof(float), stream);

    dim3 grid((OUT_W + TW - 1) / TW, (OUT_W + TH - 1) / TH, 16);  // 16 x 16 x 16
    ssim_tile_kernel<<<grid, 256, 0, stream>>>(sr, hr, accum);
    ssim_finalize<<<1, 1, 0, stream>>>(accum, out);
}

// Round 3
// 128.908 us; speedup vs baseline: 1.3103x; 1.3103x over previous
//
#include <hip/hip_runtime.h>
#include <math.h>

#define TW 32
#define TH 32
#define HR 42          // TH + 10 intermediate rows
#define IMG_W 512
#define OUT_W 502      // 512 - 11 + 1
#define CH_STRIDE (3 * IMG_W * IMG_W)
#define NBLK 4096      // 16 x 16 x 16

// Phase 1: 168 threads, each computes 8 consecutive horizontal-conv outputs
//          for one of 42 rows, loading a 20-float span straight from global
//          (float4-aligned), writing 5 intermediate fields to LDS as float4.
// Phase 2: 128 threads, each owns (column, 8-row strip): reads 18 rows x 5
//          fields ONCE each (register accumulation), applies SSIM, reduces.
__global__ __launch_bounds__(256) void ssim_main_kernel(
    const float* __restrict__ sr_img,
    const float* __restrict__ hr_img,
    float* __restrict__ partial)
{
    __shared__ float hf[5][HR][TW];   // m1, m2, x2, y2, xy  (26880 B)
    __shared__ float red[4];

    const int t  = threadIdx.x;
    const int x0 = blockIdx.x * TW;
    const int y0 = blockIdx.y * TH;
    const int b  = blockIdx.z;

    // 1D Gaussian (separable window); same numerics as reference
    float w[11];
    {
        float s = 0.f;
#pragma unroll
        for (int i = 0; i < 11; ++i) {
            float d = (float)(i - 5);
            w[i] = expf(-d * d / 4.5f);
            s += w[i];
        }
        float inv = 1.f / s;
#pragma unroll
        for (int i = 0; i < 11; ++i) w[i] *= inv;
    }

    const float* __restrict__ hrp = hr_img + (size_t)b * CH_STRIDE;  // channel 0
    const float* __restrict__ srp = sr_img + (size_t)b * CH_STRIDE;

    // ---------- Phase 1: horizontal 11-tap, direct from global ----------
    if (t < 168) {
        int r  = t >> 2;          // 0..41
        int c0 = (t & 3) * 8;     // 0,8,16,24
        int gy = y0 + r; if (gy > IMG_W - 1) gy = IMG_W - 1;
        // element offset multiple of 4 -> 16B aligned; right-edge spill stays
        // inside the allocation and only feeds discarded outputs.
        const float4* hrow = (const float4*)(hrp + (size_t)gy * IMG_W + x0 + c0);
        const float4* srow = (const float4*)(srp + (size_t)gy * IMG_W + x0 + c0);

        float h[20], s[20];
#pragma unroll
        for (int q = 0; q < 5; ++q) {
            float4 va = hrow[q];
            h[4*q] = va.x; h[4*q+1] = va.y; h[4*q+2] = va.z; h[4*q+3] = va.w;
            float4 vb = srow[q];
            s[4*q] = vb.x; s[4*q+1] = vb.y; s[4*q+2] = vb.z; s[4*q+3] = vb.w;
        }

        float m1[8], m2[8], x2[8], y2[8], xy[8];
#pragma unroll
        for (int j = 0; j < 8; ++j) { m1[j]=0.f; m2[j]=0.f; x2[j]=0.f; y2[j]=0.f; xy[j]=0.f; }
#pragma unroll
        for (int k = 0; k < 11; ++k) {
            float wk = w[k];
#pragma unroll
            for (int j = 0; j < 8; ++j) {
                float a = h[j + k], bb = s[j + k];
                float u = wk * a, v = wk * bb;
                m1[j] += u;      m2[j] += v;
                x2[j] += u * a;  y2[j] += v * bb;  xy[j] += u * bb;
            }
        }
        // write as 2x float4 per field (16B aligned: c0 multiple of 8)
        *(float4*)&hf[0][r][c0]   = make_float4(m1[0],m1[1],m1[2],m1[3]);
        *(float4*)&hf[0][r][c0+4] = make_float4(m1[4],m1[5],m1[6],m1[7]);
        *(float4*)&hf[1][r][c0]   = make_float4(m2[0],m2[1],m2[2],m2[3]);
        *(float4*)&hf[1][r][c0+4] = make_float4(m2[4],m2[5],m2[6],m2[7]);
        *(float4*)&hf[2][r][c0]   = make_float4(x2[0],x2[1],x2[2],x2[3]);
        *(float4*)&hf[2][r][c0+4] = make_float4(x2[4],x2[5],x2[6],x2[7]);
        *(float4*)&hf[3][r][c0]   = make_float4(y2[0],y2[1],y2[2],y2[3]);
        *(float4*)&hf[3][r][c0+4] = make_float4(y2[4],y2[5],y2[6],y2[7]);
        *(float4*)&hf[4][r][c0]   = make_float4(xy[0],xy[1],xy[2],xy[3]);
        *(float4*)&hf[4][r][c0+4] = make_float4(xy[4],xy[5],xy[6],xy[7]);
    }
    __syncthreads();

    // ---------- Phase 2: vertical 11-tap with single-read accumulation ----------
    const float C1 = 1e-4f, C2 = 9e-4f;
    float local = 0.f;
    if (t < 128) {
        int c  = t & 31;
        int r0 = (t >> 5) * 8;    // 0,8,16,24

        float am1[8], am2[8], ax2[8], ay2[8], axy[8];
#pragma unroll
        for (int j = 0; j < 8; ++j) { am1[j]=0.f; am2[j]=0.f; ax2[j]=0.f; ay2[j]=0.f; axy[j]=0.f; }

#pragma unroll
        for (int i = 0; i < 18; ++i) {
            float vm1 = hf[0][r0 + i][c];
            float vm2 = hf[1][r0 + i][c];
            float vx2 = hf[2][r0 + i][c];
            float vy2 = hf[3][r0 + i][c];
            float vxy = hf[4][r0 + i][c];
#pragma unroll
            for (int j = 0; j < 8; ++j) {
                int k = i - j;
                if (k >= 0 && k <= 10) {
                    float wk = w[k];
                    am1[j] += wk * vm1;  am2[j] += wk * vm2;
                    ax2[j] += wk * vx2;  ay2[j] += wk * vy2;
                    axy[j] += wk * vxy;
                }
            }
        }

        int ox = x0 + c;
#pragma unroll
        for (int j = 0; j < 8; ++j) {
            int oy = y0 + r0 + j;
            if (oy < OUT_W && ox < OUT_W) {
                float m1 = am1[j], m2 = am2[j];
                float mu1s = m1 * m1, mu2s = m2 * m2, m12 = m1 * m2;
                float s1 = ax2[j] - mu1s, s2 = ay2[j] - mu2s, s12 = axy[j] - m12;
                float num = (2.f * m12 + C1) * (2.f * s12 + C2);
                float den = (mu1s + mu2s + C1) * (s1 + s2 + C2);
                local += num / den;
            }
        }
    }

    // ---------- Reduction: wave shuffle + tiny LDS ----------
#pragma unroll
    for (int off = 32; off > 0; off >>= 1)
        local += __shfl_down(local, off);
    if ((t & 63) == 0) red[t >> 6] = local;
    __syncthreads();
    if (t == 0) {
        int blk = (blockIdx.z * gridDim.y + blockIdx.y) * gridDim.x + blockIdx.x;
        partial[blk] = red[0] + red[1] + red[2] + red[3];
    }
}

__global__ __launch_bounds__(256) void ssim_finalize(
    const float* __restrict__ partial, float* __restrict__ out)
{
    __shared__ float red[4];
    int t = threadIdx.x;
    float s = 0.f;
#pragma unroll
    for (int i = 0; i < NBLK / 256; ++i)
        s += partial[t + i * 256];
#pragma unroll
    for (int off = 32; off > 0; off >>= 1)
        s += __shfl_down(s, off);
    if ((t & 63) == 0) red[t >> 6] = s;
    __syncthreads();
    if (t == 0)
        out[0] = (red[0] + red[1] + red[2] + red[3]) * (1.0f / (16.0f * 502.0f * 502.0f));
}

extern "C" void kernel_launch(void* const* d_in, const int* in_sizes, int n_in,
                              void* d_out, int out_size, void* d_ws, size_t ws_size,
                              hipStream_t stream)
{
    const float* sr = (const float*)d_in[0];  // sr_image
    const float* hr = (const float*)d_in[1];  // hr_image
    float* out = (float*)d_out;
    float* partial = (float*)d_ws;            // 4096 floats, fully overwritten

    dim3 grid(16, 16, 16);
    ssim_main_kernel<<<grid, 256, 0, stream>>>(sr, hr, partial);
    ssim_finalize<<<1, 256, 0, stream>>>(partial, out);
}

// Round 4
// 124.383 us; speedup vs baseline: 1.3580x; 1.0364x over previous
//
#include <hip/hip_runtime.h>
#include <math.h>

#define TW 32
#define TH 32
#define HR 42          // TH + 10 intermediate rows
#define IMG_W 512
#define OUT_W 502      // 512 - 11 + 1
#define CH_STRIDE (3 * IMG_W * IMG_W)
#define NBLK 4096      // 16 x 16 x 16

// Phase 1: 168 threads, each computes 8 consecutive horizontal-conv outputs
//          for one of 42 rows, loading a 20-float span straight from global
//          (float4-aligned), writing 5 intermediate fields to LDS as float4.
// Phase 2: 256 threads, each owns (column, 4-row strip): reads 14 rows x 5
//          fields once each (register accumulation), applies SSIM, reduces.
//          All 4 waves active (R3 change: was 128 threads / 8-row strips).
__global__ __launch_bounds__(256) void ssim_main_kernel(
    const float* __restrict__ sr_img,
    const float* __restrict__ hr_img,
    float* __restrict__ partial)
{
    __shared__ float hf[5][HR][TW];   // m1, m2, x2, y2, xy  (26880 B)
    __shared__ float red[4];          // total 26896 B -> 6 blocks/CU

    const int t  = threadIdx.x;
    const int x0 = blockIdx.x * TW;
    const int y0 = blockIdx.y * TH;
    const int b  = blockIdx.z;

    // 1D Gaussian (separable window); same numerics as reference
    float w[11];
    {
        float s = 0.f;
#pragma unroll
        for (int i = 0; i < 11; ++i) {
            float d = (float)(i - 5);
            w[i] = expf(-d * d / 4.5f);
            s += w[i];
        }
        float inv = 1.f / s;
#pragma unroll
        for (int i = 0; i < 11; ++i) w[i] *= inv;
    }

    const float* __restrict__ hrp = hr_img + (size_t)b * CH_STRIDE;  // channel 0
    const float* __restrict__ srp = sr_img + (size_t)b * CH_STRIDE;

    // ---------- Phase 1: horizontal 11-tap, direct from global ----------
    if (t < 168) {
        int r  = t >> 2;          // 0..41
        int c0 = (t & 3) * 8;     // 0,8,16,24
        int gy = y0 + r; if (gy > IMG_W - 1) gy = IMG_W - 1;
        const float4* hrow = (const float4*)(hrp + (size_t)gy * IMG_W + x0 + c0);
        const float4* srow = (const float4*)(srp + (size_t)gy * IMG_W + x0 + c0);

        float h[20], s[20];
#pragma unroll
        for (int q = 0; q < 5; ++q) {
            float4 va = hrow[q];
            h[4*q] = va.x; h[4*q+1] = va.y; h[4*q+2] = va.z; h[4*q+3] = va.w;
            float4 vb = srow[q];
            s[4*q] = vb.x; s[4*q+1] = vb.y; s[4*q+2] = vb.z; s[4*q+3] = vb.w;
        }

        float m1[8], m2[8], x2[8], y2[8], xy[8];
#pragma unroll
        for (int j = 0; j < 8; ++j) { m1[j]=0.f; m2[j]=0.f; x2[j]=0.f; y2[j]=0.f; xy[j]=0.f; }
#pragma unroll
        for (int k = 0; k < 11; ++k) {
            float wk = w[k];
#pragma unroll
            for (int j = 0; j < 8; ++j) {
                float a = h[j + k], bb = s[j + k];
                float u = wk * a, v = wk * bb;
                m1[j] += u;      m2[j] += v;
                x2[j] += u * a;  y2[j] += v * bb;  xy[j] += u * bb;
            }
        }
        *(float4*)&hf[0][r][c0]   = make_float4(m1[0],m1[1],m1[2],m1[3]);
        *(float4*)&hf[0][r][c0+4] = make_float4(m1[4],m1[5],m1[6],m1[7]);
        *(float4*)&hf[1][r][c0]   = make_float4(m2[0],m2[1],m2[2],m2[3]);
        *(float4*)&hf[1][r][c0+4] = make_float4(m2[4],m2[5],m2[6],m2[7]);
        *(float4*)&hf[2][r][c0]   = make_float4(x2[0],x2[1],x2[2],x2[3]);
        *(float4*)&hf[2][r][c0+4] = make_float4(x2[4],x2[5],x2[6],x2[7]);
        *(float4*)&hf[3][r][c0]   = make_float4(y2[0],y2[1],y2[2],y2[3]);
        *(float4*)&hf[3][r][c0+4] = make_float4(y2[4],y2[5],y2[6],y2[7]);
        *(float4*)&hf[4][r][c0]   = make_float4(xy[0],xy[1],xy[2],xy[3]);
        *(float4*)&hf[4][r][c0+4] = make_float4(xy[4],xy[5],xy[6],xy[7]);
    }
    __syncthreads();

    // ---------- Phase 2: vertical 11-tap, 4-row strips, all 256 threads ----------
    const float C1 = 1e-4f, C2 = 9e-4f;
    float local = 0.f;
    {
        int c  = t & 31;
        int r0 = (t >> 5) * 4;    // 0,4,...,28

        float am1[4], am2[4], ax2[4], ay2[4], axy[4];
#pragma unroll
        for (int j = 0; j < 4; ++j) { am1[j]=0.f; am2[j]=0.f; ax2[j]=0.f; ay2[j]=0.f; axy[j]=0.f; }

#pragma unroll
        for (int i = 0; i < 14; ++i) {
            float vm1 = hf[0][r0 + i][c];
            float vm2 = hf[1][r0 + i][c];
            float vx2 = hf[2][r0 + i][c];
            float vy2 = hf[3][r0 + i][c];
            float vxy = hf[4][r0 + i][c];
#pragma unroll
            for (int j = 0; j < 4; ++j) {
                int k = i - j;
                if (k >= 0 && k <= 10) {
                    float wk = w[k];
                    am1[j] += wk * vm1;  am2[j] += wk * vm2;
                    ax2[j] += wk * vx2;  ay2[j] += wk * vy2;
                    axy[j] += wk * vxy;
                }
            }
        }

        int ox = x0 + c;
#pragma unroll
        for (int j = 0; j < 4; ++j) {
            int oy = y0 + r0 + j;
            if (oy < OUT_W && ox < OUT_W) {
                float m1 = am1[j], m2 = am2[j];
                float mu1s = m1 * m1, mu2s = m2 * m2, m12 = m1 * m2;
                float s1 = ax2[j] - mu1s, s2 = ay2[j] - mu2s, s12 = axy[j] - m12;
                float num = (2.f * m12 + C1) * (2.f * s12 + C2);
                float den = (mu1s + mu2s + C1) * (s1 + s2 + C2);
                local += num / den;
            }
        }
    }

    // ---------- Reduction: wave shuffle + tiny LDS ----------
#pragma unroll
    for (int off = 32; off > 0; off >>= 1)
        local += __shfl_down(local, off);
    if ((t & 63) == 0) red[t >> 6] = local;
    __syncthreads();
    if (t == 0) {
        int blk = (blockIdx.z * gridDim.y + blockIdx.y) * gridDim.x + blockIdx.x;
        partial[blk] = red[0] + red[1] + red[2] + red[3];
    }
}

__global__ __launch_bounds__(256) void ssim_finalize(
    const float* __restrict__ partial, float* __restrict__ out)
{
    __shared__ float red[4];
    int t = threadIdx.x;
    float s = 0.f;
#pragma unroll
    for (int i = 0; i < NBLK / 256; ++i)
        s += partial[t + i * 256];
#pragma unroll
    for (int off = 32; off > 0; off >>= 1)
        s += __shfl_down(s, off);
    if ((t & 63) == 0) red[t >> 6] = s;
    __syncthreads();
    if (t == 0)
        out[0] = (red[0] + red[1] + red[2] + red[3]) * (1.0f / (16.0f * 502.0f * 502.0f));
}

extern "C" void kernel_launch(void* const* d_in, const int* in_sizes, int n_in,
                              void* d_out, int out_size, void* d_ws, size_t ws_size,
                              hipStream_t stream)
{
    const float* sr = (const float*)d_in[0];  // sr_image
    const float* hr = (const float*)d_in[1];  // hr_image
    float* out = (float*)d_out;
    float* partial = (float*)d_ws;            // 4096 floats, fully overwritten

    dim3 grid(16, 16, 16);
    ssim_main_kernel<<<grid, 256, 0, stream>>>(sr, hr, partial);
    ssim_finalize<<<1, 256, 0, stream>>>(partial, out);
}